// Round 4
// baseline (177.126 us; speedup 1.0000x reference)
//
#include <hip/hip_runtime.h>

typedef float f4 __attribute__((ext_vector_type(4)));

#define NV 65536       // total vectors (16*4096)
#define D 64           // embedding dim
#define K 1024         // codebook size
#define LOSS_OFF 4194304
#define IDX_OFF  4194305

// Per-code squared norms, replicating numpy fp32 pairwise-8 summation exactly.
__global__ void vq_prep(const float* __restrict__ E, float* __restrict__ eSq,
                        float* __restrict__ loss) {
  int k = blockIdx.x * 256 + threadIdx.x;
  if (k == 0) *loss = 0.0f;
  if (k < K) {
    const float* row = E + (size_t)k * D;
    float r[8];
#pragma unroll
    for (int j = 0; j < 8; ++j) r[j] = __fmul_rn(row[j], row[j]);
#pragma unroll
    for (int i = 8; i < D; i += 8)
#pragma unroll
      for (int j = 0; j < 8; ++j)
        r[j] = __fadd_rn(r[j], __fmul_rn(row[i + j], row[i + j]));
    eSq[k] = __fadd_rn(
        __fadd_rn(__fadd_rn(r[0], r[1]), __fadd_rn(r[2], r[3])),
        __fadd_rn(__fadd_rn(r[4], r[5]), __fadd_rn(r[6], r[7])));
  }
}

// One vector per lane (x fully in VGPRs); 4 waves split K into quarters;
// e-rows are wave-uniform loads (no LDS in the inner loop at all).
__global__ __launch_bounds__(256, 3) void vq_main(
    const float* __restrict__ X, const float* __restrict__ E,
    const float* __restrict__ eSq, float* __restrict__ out) {
  __shared__ float redv[4][64];
  __shared__ int redi[4][64];
  __shared__ int sidx[64];

  const int t = threadIdx.x;
  const int lane = t & 63;
  const int w = __builtin_amdgcn_readfirstlane(t >> 6);  // uniform wave id
  const int bv0 = blockIdx.x * 64;

  // Load this lane's vector: 64 floats in registers, read once.
  const f4* xp = reinterpret_cast<const f4*>(X + (size_t)(bv0 + lane) * D);
  f4 xv[16];
#pragma unroll
  for (int i = 0; i < 16; ++i) xv[i] = xp[i];

  // numpy-exact ||x||^2: pairwise-8, separate mul/add rounding.
  float r[8];
#pragma unroll
  for (int j = 0; j < 8; ++j) {
    float x0 = xv[j >> 2][j & 3];
    r[j] = __fmul_rn(x0, x0);
  }
#pragma unroll
  for (int i = 1; i < 8; ++i)
#pragma unroll
    for (int j = 0; j < 8; ++j) {
      float xe = xv[2 * i + (j >> 2)][j & 3];
      r[j] = __fadd_rn(r[j], __fmul_rn(xe, xe));
    }
  const float xx = __fadd_rn(
      __fadd_rn(__fadd_rn(r[0], r[1]), __fadd_rn(r[2], r[3])),
      __fadd_rn(__fadd_rn(r[4], r[5]), __fadd_rn(r[6], r[7])));

  const f4* eb = reinterpret_cast<const f4*>(E);
  const int c0 = w * (K / 4);   // this wave's code quarter (index-ordered)

  // Half-row double buffer: hA = first 32 dims, hB = second 32 dims.
  f4 hA[8], hB[8];
#pragma unroll
  for (int i = 0; i < 8; ++i) hA[i] = eb[(size_t)c0 * 16 + i];

  float best = 3.4e38f;
  int bi = 0;

  for (int cc = 0; cc < K / 4; ++cc) {
    const int c = c0 + cc;
    const int cn = c0 + (cc < K / 4 - 1 ? cc + 1 : cc);
#pragma unroll
    for (int i = 0; i < 8; ++i) hB[i] = eb[(size_t)c * 16 + 8 + i];
    const float ee = eSq[c];

    // Dot product: single fmaf chain, d = 0..63 ascending (bit-identical to
    // the passing rounds' accumulation order).
    float m = 0.0f;
#pragma unroll
    for (int i = 0; i < 8; ++i) {
      m = fmaf(hA[i][0], xv[i][0], m);
      m = fmaf(hA[i][1], xv[i][1], m);
      m = fmaf(hA[i][2], xv[i][2], m);
      m = fmaf(hA[i][3], xv[i][3], m);
    }
    // Prefetch next code's first half while the second-half chain runs.
#pragma unroll
    for (int i = 0; i < 8; ++i) hA[i] = eb[(size_t)cn * 16 + i];
#pragma unroll
    for (int i = 0; i < 8; ++i) {
      m = fmaf(hB[i][0], xv[8 + i][0], m);
      m = fmaf(hB[i][1], xv[8 + i][1], m);
      m = fmaf(hB[i][2], xv[8 + i][2], m);
      m = fmaf(hB[i][3], xv[8 + i][3], m);
    }

    // Reference-exact fp32 score; strict < in ascending code order.
    const float A = __fadd_rn(xx, ee);
    const float dq = __fsub_rn(A, 2.0f * m);
    if (dq < best) { best = dq; bi = c; }
  }

  redv[w][lane] = best;
  redi[w][lane] = bi;
  __syncthreads();

  // Merge the 4 quarters lexicographically (quarter order == index order,
  // so (val, idx) lex-min == numpy first-occurrence).
  if (t < 64) {
    float bv = redv[0][t];
    int b = redi[0][t];
#pragma unroll
    for (int q = 1; q < 4; ++q) {
      float ov = redv[q][t];
      int oi = redi[q][t];
      if (ov < bv || (ov == bv && oi < b)) { bv = ov; b = oi; }
    }
    sidx[t] = b;
  }
  __syncthreads();

  // Epilogue: 4 threads per vector gather the winning code row, write
  // quantized output (coalesced 64B/thread), accumulate loss.
  const int vv = t >> 2, seg = t & 3;
  const int code = sidx[vv];
  const f4* er = eb + (size_t)code * 16 + seg * 4;
  const f4* xr = reinterpret_cast<const f4*>(X + (size_t)(bv0 + vv) * D) + seg * 4;
  f4* op = reinterpret_cast<f4*>(out + (size_t)(bv0 + vv) * D) + seg * 4;
  float lsum = 0.0f;
#pragma unroll
  for (int i = 0; i < 4; ++i) {
    f4 e4 = er[i], x4 = xr[i];
    float d0 = e4[0] - x4[0], d1 = e4[1] - x4[1];
    float d2 = e4[2] - x4[2], d3 = e4[3] - x4[3];
    lsum += d0 * d0 + d1 * d1 + d2 * d2 + d3 * d3;
    op[i] = e4;
  }
  if (t < 64) out[IDX_OFF + bv0 + t] = (float)sidx[t];

#pragma unroll
  for (int off = 1; off < 64; off <<= 1) lsum += __shfl_xor(lsum, off, 64);
  if (lane == 0)
    atomicAdd(out + LOSS_OFF, lsum * (1.25f / (float)(NV * (size_t)D)));
}

extern "C" void kernel_launch(void* const* d_in, const int* in_sizes, int n_in,
                              void* d_out, int out_size, void* d_ws, size_t ws_size,
                              hipStream_t stream) {
  const float* X = (const float*)d_in[0];
  const float* E = (const float*)d_in[1];
  float* out = (float*)d_out;
  float* eSq = (float*)d_ws;  // 4 KB scratch
  vq_prep<<<4, 256, 0, stream>>>(E, eSq, out + LOSS_OFF);
  vq_main<<<NV / 64, 256, 0, stream>>>(X, E, eSq, out);
}

// Round 5
// 173.921 us; speedup vs baseline: 1.0184x; 1.0184x over previous
//
#include <hip/hip_runtime.h>

typedef float f4 __attribute__((ext_vector_type(4)));

#define NV 65536       // total vectors (16*4096)
#define D 64           // embedding dim
#define K 1024         // codebook size
#define LOSS_OFF 4194304
#define IDX_OFF  4194305

// Per-code squared norms, replicating numpy fp32 pairwise-8 summation exactly.
__global__ void vq_prep(const float* __restrict__ E, float* __restrict__ eSq,
                        float* __restrict__ loss) {
  int k = blockIdx.x * 256 + threadIdx.x;
  if (k == 0) *loss = 0.0f;
  if (k < K) {
    const float* row = E + (size_t)k * D;
    float r[8];
#pragma unroll
    for (int j = 0; j < 8; ++j) r[j] = __fmul_rn(row[j], row[j]);
#pragma unroll
    for (int i = 8; i < D; i += 8)
#pragma unroll
      for (int j = 0; j < 8; ++j)
        r[j] = __fadd_rn(r[j], __fmul_rn(row[i + j], row[i + j]));
    eSq[k] = __fadd_rn(
        __fadd_rn(__fadd_rn(r[0], r[1]), __fadd_rn(r[2], r[3])),
        __fadd_rn(__fadd_rn(r[4], r[5]), __fadd_rn(r[6], r[7])));
  }
}

// ---- named-register helpers (no arrays => nothing to demote to AGPR) ----
#define DECL8(p) f4 p##0, p##1, p##2, p##3, p##4, p##5, p##6, p##7;
#define LD8(p, base, off)                                              \
  p##0 = (base)[(off) + 0]; p##1 = (base)[(off) + 1];                  \
  p##2 = (base)[(off) + 2]; p##3 = (base)[(off) + 3];                  \
  p##4 = (base)[(off) + 4]; p##5 = (base)[(off) + 5];                  \
  p##6 = (base)[(off) + 6]; p##7 = (base)[(off) + 7];
#define FMA4(m, p, x)                                                  \
  m = fmaf((p)[0], (x)[0], m); m = fmaf((p)[1], (x)[1], m);            \
  m = fmaf((p)[2], (x)[2], m); m = fmaf((p)[3], (x)[3], m);
#define CHA(m, p)                                                      \
  FMA4(m, p##0, x0) FMA4(m, p##1, x1) FMA4(m, p##2, x2)                \
  FMA4(m, p##3, x3) FMA4(m, p##4, x4) FMA4(m, p##5, x5)                \
  FMA4(m, p##6, x6) FMA4(m, p##7, x7)
#define CHB(m, p)                                                      \
  FMA4(m, p##0, x8)  FMA4(m, p##1, x9)  FMA4(m, p##2, x10)             \
  FMA4(m, p##3, x11) FMA4(m, p##4, x12) FMA4(m, p##5, x13)             \
  FMA4(m, p##6, x14) FMA4(m, p##7, x15)
#define SQ(v, e) __fmul_rn((v)[e], (v)[e])
#define NRM(a, b)                                                      \
  r0 = __fadd_rn(r0, SQ(a, 0)); r1 = __fadd_rn(r1, SQ(a, 1));          \
  r2 = __fadd_rn(r2, SQ(a, 2)); r3 = __fadd_rn(r3, SQ(a, 3));          \
  r4 = __fadd_rn(r4, SQ(b, 0)); r5 = __fadd_rn(r5, SQ(b, 1));          \
  r6 = __fadd_rn(r6, SQ(b, 2)); r7 = __fadd_rn(r7, SQ(b, 3));

// One vector per lane (x in 16 named f4 regs); 4 waves split K into quarters;
// two codes per iteration (independent fmaf chains) with half-row prefetch.
__global__ __launch_bounds__(256, 2) void vq_main(
    const float* __restrict__ X, const float* __restrict__ E,
    const float* __restrict__ eSq, float* __restrict__ out) {
  __shared__ float redv[4][64];
  __shared__ int redi[4][64];
  __shared__ int sidx[64];

  const int t = threadIdx.x;
  const int lane = t & 63;
  const int w = __builtin_amdgcn_readfirstlane(t >> 6);  // uniform wave id
  const int bv0 = blockIdx.x * 64;

  // This lane's vector: 64 floats in 16 named f4 registers, read once.
  const f4* xp = reinterpret_cast<const f4*>(X + (size_t)(bv0 + lane) * D);
  f4 x0 = xp[0], x1 = xp[1], x2 = xp[2], x3 = xp[3];
  f4 x4 = xp[4], x5 = xp[5], x6 = xp[6], x7 = xp[7];
  f4 x8 = xp[8], x9 = xp[9], x10 = xp[10], x11 = xp[11];
  f4 x12 = xp[12], x13 = xp[13], x14 = xp[14], x15 = xp[15];

  // numpy-exact ||x||^2: pairwise-8, separate mul/add rounding.
  float r0 = SQ(x0, 0), r1 = SQ(x0, 1), r2 = SQ(x0, 2), r3 = SQ(x0, 3);
  float r4 = SQ(x1, 0), r5 = SQ(x1, 1), r6 = SQ(x1, 2), r7 = SQ(x1, 3);
  NRM(x2, x3) NRM(x4, x5) NRM(x6, x7) NRM(x8, x9)
  NRM(x10, x11) NRM(x12, x13) NRM(x14, x15)
  const float xx = __fadd_rn(
      __fadd_rn(__fadd_rn(r0, r1), __fadd_rn(r2, r3)),
      __fadd_rn(__fadd_rn(r4, r5), __fadd_rn(r6, r7)));

  const f4* eb = reinterpret_cast<const f4*>(E);
  const int c0 = w * (K / 4);   // this wave's code quarter (index-ordered)

  DECL8(qa) DECL8(ra)   // half-A (dims 0..31) of codes c, c+1
  DECL8(qb) DECL8(rb)   // half-B (dims 32..63) of codes c, c+1

  {
    const f4* e0p = eb + (size_t)c0 * 16;
    LD8(qa, e0p, 0) LD8(ra, e0p, 16)
  }

  float best = 3.4e38f;
  int bi = 0;

  for (int it = 0; it < K / 8; ++it) {
    const int c = c0 + 2 * it;
    const f4* ec = eb + (size_t)c * 16;
    LD8(qb, ec, 8) LD8(rb, ec, 24)          // half-Bs of current pair
    const float ee0 = eSq[c], ee1 = eSq[c + 1];

    // Phase 1: dims 0..31, two independent chains (ascending d order kept).
    float m0 = 0.0f, m1 = 0.0f;
    CHA(m0, qa) CHA(m1, ra)

    // Prefetch next pair's half-As under phase 2's chain.
    const int cn = (it < K / 8 - 1) ? c + 2 : c;
    const f4* en = eb + (size_t)cn * 16;
    LD8(qa, en, 0) LD8(ra, en, 16)

    // Phase 2: dims 32..63.
    CHB(m0, qb) CHB(m1, rb)

    // Reference-exact fp32 score; strict < in ascending code order.
    const float A0 = __fadd_rn(xx, ee0);
    const float dq0 = __fsub_rn(A0, 2.0f * m0);
    if (dq0 < best) { best = dq0; bi = c; }
    const float A1 = __fadd_rn(xx, ee1);
    const float dq1 = __fsub_rn(A1, 2.0f * m1);
    if (dq1 < best) { best = dq1; bi = c + 1; }
  }

  redv[w][lane] = best;
  redi[w][lane] = bi;
  __syncthreads();

  // Merge the 4 quarters lexicographically (quarter order == index order,
  // so (val, idx) lex-min == numpy first-occurrence).
  if (t < 64) {
    float bv = redv[0][t];
    int b = redi[0][t];
#pragma unroll
    for (int q = 1; q < 4; ++q) {
      float ov = redv[q][t];
      int oi = redi[q][t];
      if (ov < bv || (ov == bv && oi < b)) { bv = ov; b = oi; }
    }
    sidx[t] = b;
  }
  __syncthreads();

  // Epilogue: 4 threads per vector gather the winning code row, write
  // quantized output (coalesced), accumulate loss.
  const int vv = t >> 2, seg = t & 3;
  const int code = sidx[vv];
  const f4* er = eb + (size_t)code * 16 + seg * 4;
  const f4* xr = reinterpret_cast<const f4*>(X + (size_t)(bv0 + vv) * D) + seg * 4;
  f4* op = reinterpret_cast<f4*>(out + (size_t)(bv0 + vv) * D) + seg * 4;
  float lsum = 0.0f;
#pragma unroll
  for (int i = 0; i < 4; ++i) {
    f4 e4 = er[i], xv4 = xr[i];
    float d0 = e4[0] - xv4[0], d1 = e4[1] - xv4[1];
    float d2 = e4[2] - xv4[2], d3 = e4[3] - xv4[3];
    lsum += d0 * d0 + d1 * d1 + d2 * d2 + d3 * d3;
    op[i] = e4;
  }
  if (t < 64) out[IDX_OFF + bv0 + t] = (float)sidx[t];

#pragma unroll
  for (int off = 1; off < 64; off <<= 1) lsum += __shfl_xor(lsum, off, 64);
  if (lane == 0)
    atomicAdd(out + LOSS_OFF, lsum * (1.25f / (float)(NV * (size_t)D)));
}

extern "C" void kernel_launch(void* const* d_in, const int* in_sizes, int n_in,
                              void* d_out, int out_size, void* d_ws, size_t ws_size,
                              hipStream_t stream) {
  const float* X = (const float*)d_in[0];
  const float* E = (const float*)d_in[1];
  float* out = (float*)d_out;
  float* eSq = (float*)d_ws;  // 4 KB scratch
  vq_prep<<<4, 256, 0, stream>>>(E, eSq, out + LOSS_OFF);
  vq_main<<<NV / 64, 256, 0, stream>>>(X, E, eSq, out);
}